// Round 7
// baseline (515.222 us; speedup 1.0000x reference)
//
#include <hip/hip_runtime.h>
#include <hip/hip_fp16.h>

typedef _Float16 f16;
typedef _Float16 half8 __attribute__((ext_vector_type(8)));
typedef _Float16 half4v __attribute__((ext_vector_type(4)));
typedef float f32x4 __attribute__((ext_vector_type(4)));

#define NBAT 4
#define NT   2048
#define NC   2048
#define NHEAD 16
#define HD   128
#define NM   8192            // NBAT*NT rows
#define N3C  6144
#define QK_LD 4096           // row stride of the Q|K buffer (elems)
#define ATT_SCALE 0.088388347648318447f   // 1/sqrt(128)

static __device__ __forceinline__ void gload16(const void* g, void* l) {
  __builtin_amdgcn_global_load_lds(
      (const __attribute__((address_space(1))) unsigned int*)g,
      (__attribute__((address_space(3))) unsigned int*)l, 16, 0, 0);
}

// ---------------- converts ----------------

__global__ __launch_bounds__(256) void cvt_x_f16(const float* __restrict__ in,
                                                 f16* __restrict__ out) {
  size_t i = ((size_t)blockIdx.x * 256 + threadIdx.x) * 8;
  float4 a = *(const float4*)(in + i);
  float4 b = *(const float4*)(in + i + 4);
  half8 o;
  o[0] = (f16)a.x; o[1] = (f16)a.y; o[2] = (f16)a.z; o[3] = (f16)a.w;
  o[4] = (f16)b.x; o[5] = (f16)b.y; o[6] = (f16)b.z; o[7] = (f16)b.w;
  *(half8*)(out + i) = o;
}

// in: [R][CC] f32  ->  out: [CC][R] f16
__global__ __launch_bounds__(256) void cvt_tr_f16(const float* __restrict__ in,
                                                  f16* __restrict__ out,
                                                  int R, int CC) {
  __shared__ float tile[32][33];
  int cb = blockIdx.x * 32, rb = blockIdx.y * 32;
  int lx = threadIdx.x & 31, ly = threadIdx.x >> 5;  // ly 0..7
  for (int i = 0; i < 32; i += 8)
    tile[ly + i][lx] = in[(size_t)(rb + ly + i) * CC + cb + lx];
  __syncthreads();
  for (int i = 0; i < 32; i += 8)
    out[(size_t)(cb + ly + i) * R + rb + lx] = (f16)tile[lx][ly + i];
}

// ---- GEMM 256x256, BK=64, 8 waves, 8-PHASE schedule (T3+T4+T5) ----
// Same schedule/ledger as r6 (proven). Changes r7: 2D XCD tiling, vT 8B stores.
// LDS: sA/sB = [2 dbuf][2 half][128 rows x 64 K] f16, 128 KB total.
// Stage plan and vmcnt ledger: see r6 comments (unchanged):
//   p0: Ah0@v->b1  p1: Ah1@v->b1  p2: Bh0@u+2->b0  p3: Bh1@u+2->b0 [vmcnt4]
//   p4: Ah0@u+2->b0 p5: Ah1@u+2->b0 p6: Bh0@v+2->b1 p7: Bh1@v+2->b1 [vmcnt4]
template <int OUTMODE>
__global__ __launch_bounds__(512, 2)
void gemm256(const f16* __restrict__ A, const f16* __restrict__ BT,
             const float* __restrict__ bias,
             f16* __restrict__ oqk, f16* __restrict__ ovT,
             float* __restrict__ of32, int N, int K, int nbn) {
  __shared__ f16 sA[4 * 8192];   // [buf*2+half][128*64]
  __shared__ f16 sB[4 * 8192];

  const int tid = threadIdx.x;
  const int wv = tid >> 6, lane = tid & 63;
  const int lr = lane & 15, lg = lane >> 4;
  const int wm = wv >> 2, wn = wv & 3;   // 2 x 4 wave grid

  // 2D XCD tiling: xcd -> (4 bm-chunks x 2 bn-chunks); per-XCD 8 bm x nbn/2 bn.
  // Working set/XCD: 8 A-panels + nbn/2 B-panels (12 MB for QKV vs 28 MB 1D).
  const int bid = blockIdx.x;
  const int xcd = bid & 7, li = bid >> 3;
  const int bm = (xcd & 3) * 8 + (li & 7);
  const int bn = (xcd >> 2) * (nbn >> 1) + (li >> 3);

  // staging map (r3-proven): thread covers LDS 16B chunks g = j*512+tid, j=0,1.
  // q = g>>3 (row in half, 0..127), c = g&7, source k-chunk = c^(q&7).
  const int q0 = tid >> 3;                     // 0..63 (j adds 64)
  const int cx = (tid & 7) ^ (q0 & 7);
  const f16* aSrc = A + (size_t)(bm * 256 + q0) * K + cx * 8;
  const f16* bSrc = BT + (size_t)(bn * 256 + q0) * K + cx * 8;
  const size_t rs64 = (size_t)64 * K, rs128 = (size_t)128 * K;

  const int NKT = K >> 6, NIT = NKT >> 1;
  f32x4 acc[8][4] = {};

  auto stgA = [&](int t, int h, int bu) {
    const f16* s = aSrc + (size_t)h * rs128 + t * 64;
    f16* d = sA + (bu * 2 + h) * 8192 + tid * 8;
    gload16(s, d);
    gload16(s + rs64, d + 4096);
  };
  auto stgB = [&](int t, int h, int bu) {
    const f16* s = bSrc + (size_t)h * rs128 + t * 64;
    f16* d = sB + (bu * 2 + h) * 8192 + tid * 8;
    gload16(s, d);
    gload16(s + rs64, d + 4096);
  };

  // prologue
  stgA(0, 0, 0); stgA(0, 1, 0);
  stgB(0, 0, 0); stgB(0, 1, 0);
  stgB(1, 0, 1); stgB(1, 1, 1);
  asm volatile("s_waitcnt vmcnt(4)" ::: "memory");
  __builtin_amdgcn_s_barrier();
  asm volatile("" ::: "memory");

  const int xcs[2] = {((0 * 4 + lg) ^ (lr & 7)) * 8, ((1 * 4 + lg) ^ (lr & 7)) * 8};

  for (int it = 0; it < NIT; ++it) {
    const int u = 2 * it, v = u + 1;
    const bool notlast = (it < NIT - 1);
    half8 bfrag[4][2];
#pragma unroll
    for (int p = 0; p < 8; ++p) {
      const int buf = (p < 4) ? 0 : 1;
      const f16* bA = sA + (buf * 2 + wm) * 8192;
      const f16* bB = sB + (buf * 2 + (wn >> 1)) * 8192;
      const int mf0 = (p & 3) * 2;
      // ds-reads for this phase
      if ((p & 3) == 0) {
#pragma unroll
        for (int nf = 0; nf < 4; ++nf)
#pragma unroll
          for (int ks = 0; ks < 2; ++ks)
            bfrag[nf][ks] = *(const half8*)(
                bB + ((wn & 1) * 64 + nf * 16 + lr) * 64 + xcs[ks]);
      }
      half8 afrag[2][2];
#pragma unroll
      for (int m2 = 0; m2 < 2; ++m2)
#pragma unroll
        for (int ks = 0; ks < 2; ++ks)
          afrag[m2][ks] = *(const half8*)(
              bA + ((mf0 + m2) * 16 + lr) * 64 + xcs[ks]);
      // stage one half-tile
      switch (p) {
        case 0: stgA(v, 0, 1); break;
        case 1: stgA(v, 1, 1); break;
        case 2: if (notlast) stgB(u + 2, 0, 0); break;
        case 3: if (notlast) stgB(u + 2, 1, 0); break;
        case 4: if (notlast) stgA(u + 2, 0, 0); break;
        case 5: if (notlast) stgA(u + 2, 1, 0); break;
        case 6: if (notlast) stgB(v + 2, 0, 1); break;
        case 7: if (notlast) stgB(v + 2, 1, 1); break;
      }
      // gate (counted, never 0 except last iteration)
      if ((p & 3) == 3) {
        if (notlast) asm volatile("s_waitcnt vmcnt(4)" ::: "memory");
        else         asm volatile("s_waitcnt vmcnt(0)" ::: "memory");
      }
      asm volatile("" ::: "memory");
      __builtin_amdgcn_s_barrier();
      asm volatile("" ::: "memory");
      __builtin_amdgcn_s_setprio(1);
#pragma unroll
      for (int m2 = 0; m2 < 2; ++m2)
#pragma unroll
        for (int nf = 0; nf < 4; ++nf)
#pragma unroll
          for (int ks = 0; ks < 2; ++ks)
            acc[mf0 + m2][nf] = __builtin_amdgcn_mfma_f32_16x16x32_f16(
                afrag[m2][ks], bfrag[nf][ks], acc[mf0 + m2][nf], 0, 0, 0);
      __builtin_amdgcn_s_setprio(0);
      asm volatile("" ::: "memory");
      __builtin_amdgcn_s_barrier();
    }
  }

  // epilogue
#pragma unroll
  for (int nf = 0; nf < 4; ++nf) {
    const int col = bn * 256 + wn * 64 + nf * 16 + lr;
    const float bv = bias[col];
#pragma unroll
    for (int mf = 0; mf < 8; ++mf) {
      const int row0 = bm * 256 + wm * 128 + mf * 16 + lg * 4;
      f32x4 v = acc[mf][nf];
      if (OUTMODE == 0) {
#pragma unroll
        for (int r = 0; r < 4; ++r)
          of32[(size_t)(row0 + r) * N + col] = v[r] + bv;
      } else {
        if (col < 4096) {
#pragma unroll
          for (int r = 0; r < 4; ++r)
            oqk[(size_t)(row0 + r) * QK_LD + col] = (f16)(v[r] + bv);
        } else {
          // vT scatter: 4 r-values are tt-consecutive -> one 8B store
          const int dfull = col - 4096;
          const int hh = dfull >> 7, dd = dfull & 127;
          const int bb = row0 >> 11, tt0 = row0 & 2047;
          half4v pk;
#pragma unroll
          for (int r = 0; r < 4; ++r) pk[r] = (f16)(v[r] + bv);
          *(half4v*)(ovT + ((size_t)(bb * NHEAD + hh) * HD + dd) * NT + tt0) = pk;
        }
      }
    }
  }
}

// ---------------- flash attention (dbuf, counted vmcnt, QBLK=128) ----------------
// qk: [8192][4096] f16 (Q cols 0..2047, K cols 2048..4095)
// vT: [b*16+h][128][2048] f16
// y : [8192][2048] f16  (row = b*T+t, col = h*128+d)
__global__ __launch_bounds__(256, 2)
void attn_fwd(const f16* __restrict__ qk, const f16* __restrict__ vT,
              f16* __restrict__ y) {
  const int bid = blockIdx.x;
  const int sid = (bid & 7) * 128 + (bid >> 3);  // bijective XCD swizzle (1024 % 8 == 0)
  const int qt = sid & 15;       // 16 q-tiles of 128 rows
  const int bh = sid >> 4;       // b*16+h
  const int b = bh >> 4, h = bh & 15;
  const int tid = threadIdx.x, w = tid >> 6, lane = tid & 63;
  const int lr = lane & 15, lg = lane >> 4;

  __shared__ f16 Ks[2][64 * 128];    // 2 x 16 KB, XOR-swizzled rows
  __shared__ f16 Vs[2][128 * 64];    // 2 x 16 KB, V^T rows, XOR-swizzled
  __shared__ f16 Ps[4][2][16 * 64];  // per wave, per stripe P tile (16 KB)

  // Q fragments: stripes s=0,1 -> rows qt*128 + w*32 + s*16 + lr
  half8 qf[2][4];
  for (int s = 0; s < 2; ++s) {
    const f16* qp = qk + (size_t)(b * NT + qt * 128 + w * 32 + s * 16 + lr) * QK_LD +
                    h * HD + lg * 8;
    for (int dc = 0; dc < 4; ++dc) qf[s][dc] = *(const half8*)(qp + dc * 32);
  }

  f32x4 accy[2][8] = {};
  float lsum[2][4] = {};
  float mrow[2][4];
  for (int s = 0; s < 2; ++s)
    for (int r = 0; r < 4; ++r) mrow[s][r] = -1e30f;

  // staging source bases (per-lane, pre-swizzled global addresses)
  const char* kbase[4];
  const char* vbase[4];
  for (int j = 0; j < 4; ++j) {
    int idx = w * 4 + j;
    {
      int row = idx * 4 + lg;                  // kv row in tile
      int swz = (lr * 16) ^ ((row & 7) << 4);  // byte offset in 256B row
      kbase[j] = (const char*)qk +
                 ((size_t)(b * NT + row) * QK_LD + 2048 + h * HD) * 2 + swz;
    }
    {
      int d = idx * 8 + (lane >> 3);
      int cj = (lane & 7) ^ (d & 7);           // 16B source chunk in 128B row
      vbase[j] = (const char*)vT + ((size_t)(bh * HD + d) * NT + cj * 8) * 2;
    }
  }

  // prologue: stage tile 0 -> buf 0 (gated by body 0's vmcnt)
  for (int j = 0; j < 4; ++j) {
    int idx = w * 4 + j;
    gload16(kbase[j], (void*)((char*)Ks[0] + idx * 1024));
    gload16(vbase[j], (void*)((char*)Vs[0] + idx * 1024));
  }

  int cur = 0;
  for (int kt = 0; kt < 32; ++kt) {
    // issue next tile's staging into the other buffer (stays in flight past gate)
    if (kt + 1 < 32) {
      for (int j = 0; j < 4; ++j) {
        int idx = w * 4 + j;
        gload16(kbase[j] + (size_t)(kt + 1) * (64 * QK_LD * 2),
                (void*)((char*)Ks[cur ^ 1] + idx * 1024));
        gload16(vbase[j] + (size_t)(kt + 1) * 128,
                (void*)((char*)Vs[cur ^ 1] + idx * 1024));
      }
    }
    if (kt < 31) asm volatile("s_waitcnt vmcnt(8)" ::: "memory");
    else         asm volatile("s_waitcnt vmcnt(0)" ::: "memory");
    __builtin_amdgcn_s_barrier();
    asm volatile("" ::: "memory");

    // S = Q K^T : both stripes share each K fragment
    f32x4 sa[2][4] = {};
    for (int nb = 0; nb < 4; ++nb) {
      int kvr = nb * 16 + lr;
      const char* kr = (const char*)Ks[cur] + kvr * 256;
      int s7 = (kvr & 7) << 4;
      for (int dc = 0; dc < 4; ++dc) {
        half8 kb = *(const half8*)(kr + ((dc * 64 + lg * 16) ^ s7));
        sa[0][nb] = __builtin_amdgcn_mfma_f32_16x16x32_f16(qf[0][dc], kb, sa[0][nb], 0, 0, 0);
        sa[1][nb] = __builtin_amdgcn_mfma_f32_16x16x32_f16(qf[1][dc], kb, sa[1][nb], 0, 0, 0);
      }
    }

    // online softmax per stripe (defer-max; row-sum on VALU via 16-lane shuffle)
    for (int s = 0; s < 2; ++s) {
      float sv[4][4];
      float pml[4] = {-1e30f, -1e30f, -1e30f, -1e30f};
      for (int nb = 0; nb < 4; ++nb)
        for (int r = 0; r < 4; ++r) {
          float x = sa[s][nb][r] * ATT_SCALE;
          sv[nb][r] = x;
          pml[r] = fmaxf(pml[r], x);
        }
      bool ok = true;
      for (int r = 0; r < 4; ++r) ok &= (pml[r] <= mrow[s][r] + 8.0f);
      if (!__all(ok)) {
        for (int r = 0; r < 4; ++r) {
          for (int off = 1; off < 16; off <<= 1)
            pml[r] = fmaxf(pml[r], __shfl_xor(pml[r], off));
          float mn = fmaxf(mrow[s][r], pml[r]);
          float al = __expf(mrow[s][r] - mn);
          mrow[s][r] = mn;
          lsum[s][r] *= al;
          for (int db = 0; db < 8; ++db) accy[s][db][r] *= al;
        }
      }
      float rs[4] = {0.f, 0.f, 0.f, 0.f};
      for (int nb = 0; nb < 4; ++nb)
        for (int r = 0; r < 4; ++r) {
          float p = __expf(sv[nb][r] - mrow[s][r]);
          rs[r] += p;
          int prow = lg * 4 + r;
          int chunk = (nb * 2 + (lr >> 3)) ^ (prow & 7);
          Ps[w][s][prow * 64 + chunk * 8 + (lr & 7)] = (f16)p;
        }
      for (int r = 0; r < 4; ++r) {
        for (int off = 1; off < 16; off <<= 1) rs[r] += __shfl_xor(rs[r], off);
        lsum[s][r] += rs[r];
      }
    }

    // P fragments for both stripes
    half8 pa[2][2];
    for (int s = 0; s < 2; ++s)
      for (int kc = 0; kc < 2; ++kc) {
        int chunk = (kc * 4 + lg) ^ (lr & 7);
        pa[s][kc] = *(const half8*)(&Ps[w][s][lr * 64 + chunk * 8]);
      }

    // PV: both stripes share each V fragment
    for (int db = 0; db < 8; ++db) {
      int d = db * 16 + lr;
      const char* vr = (const char*)Vs[cur] + d * 128;
      int d7 = d & 7;
      for (int kc = 0; kc < 2; ++kc) {
        half8 vb = *(const half8*)(vr + (((kc * 4 + lg) ^ d7) * 16));
        accy[0][db] = __builtin_amdgcn_mfma_f32_16x16x32_f16(pa[0][kc], vb, accy[0][db], 0, 0, 0);
        accy[1][db] = __builtin_amdgcn_mfma_f32_16x16x32_f16(pa[1][kc], vb, accy[1][db], 0, 0, 0);
      }
    }

    asm volatile("" ::: "memory");
    __builtin_amdgcn_s_barrier();   // all reads of buf cur done; buf free for kt+2
    cur ^= 1;
  }

  for (int s = 0; s < 2; ++s) {
    f32x4 inv;
    for (int r = 0; r < 4; ++r) inv[r] = 1.0f / lsum[s][r];
    f16* yp = y + (size_t)(b * NT + qt * 128 + w * 32 + s * 16 + lg * 4) * NC +
              h * HD + lr;
    for (int db = 0; db < 8; ++db)
      for (int r = 0; r < 4; ++r)
        yp[(size_t)r * NC + db * 16] = (f16)(accy[s][db][r] * inv[r]);
  }
}

// ---------------- launcher ----------------
extern "C" void kernel_launch(void* const* d_in, const int* in_sizes, int n_in,
                              void* d_out, int out_size, void* d_ws, size_t ws_size,
                              hipStream_t stream) {
  (void)in_sizes; (void)n_in; (void)out_size; (void)ws_size;
  const float* x      = (const float*)d_in[0];
  const float* w_attn = (const float*)d_in[1];
  const float* b_attn = (const float*)d_in[2];
  const float* w_proj = (const float*)d_in[3];
  const float* b_proj = (const float*)d_in[4];
  float* out = (float*)d_out;

  char* p = (char*)d_ws;
  f16* xh  = (f16*)p; p += (size_t)NM * NC * 2;          // 33.5 MB
  f16* waT = (f16*)p; p += (size_t)N3C * NC * 2;         // 25.2 MB
  f16* wpT = (f16*)p; p += (size_t)NC * NC * 2;          //  8.4 MB
  f16* qkb = (f16*)p; p += (size_t)NM * QK_LD * 2;       // 67.1 MB
  f16* vT  = (f16*)p; p += (size_t)NBAT * NHEAD * HD * NT * 2; // 33.5 MB
  f16* yh  = (f16*)p; p += (size_t)NM * NC * 2;          // 33.5 MB

  cvt_x_f16<<<8192, 256, 0, stream>>>(x, xh);
  cvt_tr_f16<<<dim3(192, 64), 256, 0, stream>>>(w_attn, waT, NC, N3C);
  cvt_tr_f16<<<dim3(64, 64), 256, 0, stream>>>(w_proj, wpT, NC, NC);
  // QKV: M=8192 -> 32 bm, N=6144 -> 24 bn, 768 blocks (div by 8)
  gemm256<1><<<768, 512, 0, stream>>>(xh, waT, b_attn, qkb, vT, nullptr,
                                      N3C, NC, 24);
  attn_fwd<<<1024, 256, 0, stream>>>(qkb, vT, yh);
  // proj: M=8192 -> 32 bm, N=2048 -> 8 bn, 256 blocks (div by 8)
  gemm256<0><<<256, 512, 0, stream>>>(yh, wpT, b_proj, nullptr, nullptr,
                                      out, NC, NC, 8);
}

// Round 8
// 472.828 us; speedup vs baseline: 1.0897x; 1.0897x over previous
//
#include <hip/hip_runtime.h>
#include <hip/hip_fp16.h>

typedef _Float16 f16;
typedef _Float16 half8 __attribute__((ext_vector_type(8)));
typedef _Float16 half4v __attribute__((ext_vector_type(4)));
typedef float f32x4 __attribute__((ext_vector_type(4)));

#define NBAT 4
#define NT   2048
#define NC   2048
#define NHEAD 16
#define HD   128
#define NM   8192            // NBAT*NT rows
#define N3C  6144
#define QK_LD 4096           // row stride of the Q|K buffer (elems)
#define ATT_SCALE 0.088388347648318447f   // 1/sqrt(128), folded into Q at QKV epilogue

static __device__ __forceinline__ void gload16(const void* g, void* l) {
  __builtin_amdgcn_global_load_lds(
      (const __attribute__((address_space(1))) unsigned int*)g,
      (__attribute__((address_space(3))) unsigned int*)l, 16, 0, 0);
}

// ---------------- converts ----------------

__global__ __launch_bounds__(256) void cvt_x_f16(const float* __restrict__ in,
                                                 f16* __restrict__ out) {
  size_t i = ((size_t)blockIdx.x * 256 + threadIdx.x) * 8;
  float4 a = *(const float4*)(in + i);
  float4 b = *(const float4*)(in + i + 4);
  half8 o;
  o[0] = (f16)a.x; o[1] = (f16)a.y; o[2] = (f16)a.z; o[3] = (f16)a.w;
  o[4] = (f16)b.x; o[5] = (f16)b.y; o[6] = (f16)b.z; o[7] = (f16)b.w;
  *(half8*)(out + i) = o;
}

// in: [R][CC] f32  ->  out: [CC][R] f16
__global__ __launch_bounds__(256) void cvt_tr_f16(const float* __restrict__ in,
                                                  f16* __restrict__ out,
                                                  int R, int CC) {
  __shared__ float tile[32][33];
  int cb = blockIdx.x * 32, rb = blockIdx.y * 32;
  int lx = threadIdx.x & 31, ly = threadIdx.x >> 5;  // ly 0..7
  for (int i = 0; i < 32; i += 8)
    tile[ly + i][lx] = in[(size_t)(rb + ly + i) * CC + cb + lx];
  __syncthreads();
  for (int i = 0; i < 32; i += 8)
    out[(size_t)(cb + ly + i) * R + rb + lx] = (f16)tile[lx][ly + i];
}

// ---- GEMM 256x256, BK=64, 8 waves, 8-PHASE schedule (T3+T4+T5) ----
// Schedule/ledger as r6 (proven). r7 additions kept: 2D XCD tiling, vT 8B stores.
// r8: OUTMODE 1 scales Q columns (col<2048) by ATT_SCALE in the epilogue.
//   p0: Ah0@v->b1  p1: Ah1@v->b1  p2: Bh0@u+2->b0  p3: Bh1@u+2->b0 [vmcnt4]
//   p4: Ah0@u+2->b0 p5: Ah1@u+2->b0 p6: Bh0@v+2->b1 p7: Bh1@v+2->b1 [vmcnt4]
template <int OUTMODE>
__global__ __launch_bounds__(512, 2)
void gemm256(const f16* __restrict__ A, const f16* __restrict__ BT,
             const float* __restrict__ bias,
             f16* __restrict__ oqk, f16* __restrict__ ovT,
             float* __restrict__ of32, int N, int K, int nbn) {
  __shared__ f16 sA[4 * 8192];   // [buf*2+half][128*64]
  __shared__ f16 sB[4 * 8192];

  const int tid = threadIdx.x;
  const int wv = tid >> 6, lane = tid & 63;
  const int lr = lane & 15, lg = lane >> 4;
  const int wm = wv >> 2, wn = wv & 3;   // 2 x 4 wave grid

  // 2D XCD tiling: xcd -> (4 bm-chunks x 2 bn-chunks); per-XCD 8 bm x nbn/2 bn.
  const int bid = blockIdx.x;
  const int xcd = bid & 7, li = bid >> 3;
  const int bm = (xcd & 3) * 8 + (li & 7);
  const int bn = (xcd >> 2) * (nbn >> 1) + (li >> 3);

  // staging map (r3-proven): thread covers LDS 16B chunks g = j*512+tid, j=0,1.
  // q = g>>3 (row in half, 0..127), c = g&7, source k-chunk = c^(q&7).
  const int q0 = tid >> 3;                     // 0..63 (j adds 64)
  const int cx = (tid & 7) ^ (q0 & 7);
  const f16* aSrc = A + (size_t)(bm * 256 + q0) * K + cx * 8;
  const f16* bSrc = BT + (size_t)(bn * 256 + q0) * K + cx * 8;
  const size_t rs64 = (size_t)64 * K, rs128 = (size_t)128 * K;

  const int NKT = K >> 6, NIT = NKT >> 1;
  f32x4 acc[8][4] = {};

  auto stgA = [&](int t, int h, int bu) {
    const f16* s = aSrc + (size_t)h * rs128 + t * 64;
    f16* d = sA + (bu * 2 + h) * 8192 + tid * 8;
    gload16(s, d);
    gload16(s + rs64, d + 4096);
  };
  auto stgB = [&](int t, int h, int bu) {
    const f16* s = bSrc + (size_t)h * rs128 + t * 64;
    f16* d = sB + (bu * 2 + h) * 8192 + tid * 8;
    gload16(s, d);
    gload16(s + rs64, d + 4096);
  };

  // prologue
  stgA(0, 0, 0); stgA(0, 1, 0);
  stgB(0, 0, 0); stgB(0, 1, 0);
  stgB(1, 0, 1); stgB(1, 1, 1);
  asm volatile("s_waitcnt vmcnt(4)" ::: "memory");
  __builtin_amdgcn_s_barrier();
  asm volatile("" ::: "memory");

  const int xcs[2] = {((0 * 4 + lg) ^ (lr & 7)) * 8, ((1 * 4 + lg) ^ (lr & 7)) * 8};

  for (int it = 0; it < NIT; ++it) {
    const int u = 2 * it, v = u + 1;
    const bool notlast = (it < NIT - 1);
    half8 bfrag[4][2];
#pragma unroll
    for (int p = 0; p < 8; ++p) {
      const int buf = (p < 4) ? 0 : 1;
      const f16* bA = sA + (buf * 2 + wm) * 8192;
      const f16* bB = sB + (buf * 2 + (wn >> 1)) * 8192;
      const int mf0 = (p & 3) * 2;
      // ds-reads for this phase
      if ((p & 3) == 0) {
#pragma unroll
        for (int nf = 0; nf < 4; ++nf)
#pragma unroll
          for (int ks = 0; ks < 2; ++ks)
            bfrag[nf][ks] = *(const half8*)(
                bB + ((wn & 1) * 64 + nf * 16 + lr) * 64 + xcs[ks]);
      }
      half8 afrag[2][2];
#pragma unroll
      for (int m2 = 0; m2 < 2; ++m2)
#pragma unroll
        for (int ks = 0; ks < 2; ++ks)
          afrag[m2][ks] = *(const half8*)(
              bA + ((mf0 + m2) * 16 + lr) * 64 + xcs[ks]);
      // stage one half-tile
      switch (p) {
        case 0: stgA(v, 0, 1); break;
        case 1: stgA(v, 1, 1); break;
        case 2: if (notlast) stgB(u + 2, 0, 0); break;
        case 3: if (notlast) stgB(u + 2, 1, 0); break;
        case 4: if (notlast) stgA(u + 2, 0, 0); break;
        case 5: if (notlast) stgA(u + 2, 1, 0); break;
        case 6: if (notlast) stgB(v + 2, 0, 1); break;
        case 7: if (notlast) stgB(v + 2, 1, 1); break;
      }
      // gate (counted, never 0 except last iteration)
      if ((p & 3) == 3) {
        if (notlast) asm volatile("s_waitcnt vmcnt(4)" ::: "memory");
        else         asm volatile("s_waitcnt vmcnt(0)" ::: "memory");
      }
      asm volatile("" ::: "memory");
      __builtin_amdgcn_s_barrier();
      asm volatile("" ::: "memory");
      __builtin_amdgcn_s_setprio(1);
#pragma unroll
      for (int m2 = 0; m2 < 2; ++m2)
#pragma unroll
        for (int nf = 0; nf < 4; ++nf)
#pragma unroll
          for (int ks = 0; ks < 2; ++ks)
            acc[mf0 + m2][nf] = __builtin_amdgcn_mfma_f32_16x16x32_f16(
                afrag[m2][ks], bfrag[nf][ks], acc[mf0 + m2][nf], 0, 0, 0);
      __builtin_amdgcn_s_setprio(0);
      asm volatile("" ::: "memory");
      __builtin_amdgcn_s_barrier();
    }
  }

  // epilogue
#pragma unroll
  for (int nf = 0; nf < 4; ++nf) {
    const int col = bn * 256 + wn * 64 + nf * 16 + lr;
    const float bv = bias[col];
#pragma unroll
    for (int mf = 0; mf < 8; ++mf) {
      const int row0 = bm * 256 + wm * 128 + mf * 16 + lg * 4;
      f32x4 v = acc[mf][nf];
      if (OUTMODE == 0) {
#pragma unroll
        for (int r = 0; r < 4; ++r)
          of32[(size_t)(row0 + r) * N + col] = v[r] + bv;
      } else {
        if (col < 4096) {
          const float sc = (col < 2048) ? ATT_SCALE : 1.0f;  // fold 1/sqrt(hd) into Q
#pragma unroll
          for (int r = 0; r < 4; ++r)
            oqk[(size_t)(row0 + r) * QK_LD + col] = (f16)((v[r] + bv) * sc);
        } else {
          // vT scatter: 4 r-values are tt-consecutive -> one 8B store
          const int dfull = col - 4096;
          const int hh = dfull >> 7, dd = dfull & 127;
          const int bb = row0 >> 11, tt0 = row0 & 2047;
          half4v pk;
#pragma unroll
          for (int r = 0; r < 4; ++r) pk[r] = (f16)(v[r] + bv);
          *(half4v*)(ovT + ((size_t)(bb * NHEAD + hh) * HD + dd) * NT + tt0) = pk;
        }
      }
    }
  }
}

// ---------------- flash attention (dbuf, counted vmcnt, QBLK=128) ----------------
// qk: [8192][4096] f16 (Q cols pre-scaled by 1/sqrt(hd); K cols 2048..4095)
// vT: [b*16+h][128][2048] f16
// y : [8192][2048] f16  (row = b*T+t, col = h*128+d)
__global__ __launch_bounds__(256, 2)
void attn_fwd(const f16* __restrict__ qk, const f16* __restrict__ vT,
              f16* __restrict__ y) {
  const int bid = blockIdx.x;
  const int sid = (bid & 7) * 128 + (bid >> 3);  // bijective XCD swizzle (1024 % 8 == 0)
  const int qt = sid & 15;       // 16 q-tiles of 128 rows
  const int bh = sid >> 4;       // b*16+h
  const int b = bh >> 4, h = bh & 15;
  const int tid = threadIdx.x, w = tid >> 6, lane = tid & 63;
  const int lr = lane & 15, lg = lane >> 4;

  __shared__ f16 Ks[2][64 * 128];    // 2 x 16 KB, XOR-swizzled rows
  __shared__ f16 Vs[2][128 * 64];    // 2 x 16 KB, V^T rows, XOR-swizzled
  __shared__ f16 Ps[4][2][16 * 64];  // per wave, per stripe P tile (16 KB)

  // Q fragments: stripes s=0,1 -> rows qt*128 + w*32 + s*16 + lr
  half8 qf[2][4];
  for (int s = 0; s < 2; ++s) {
    const f16* qp = qk + (size_t)(b * NT + qt * 128 + w * 32 + s * 16 + lr) * QK_LD +
                    h * HD + lg * 8;
    for (int dc = 0; dc < 4; ++dc) qf[s][dc] = *(const half8*)(qp + dc * 32);
  }

  f32x4 accy[2][8] = {};
  f32x4 lacc[2] = {};
  float mrow[2][4];
  for (int s = 0; s < 2; ++s)
    for (int r = 0; r < 4; ++r) mrow[s][r] = -1e30f;

  half8 onev;
  for (int j = 0; j < 8; ++j) onev[j] = (f16)1.0f;

  // staging source bases (per-lane, pre-swizzled global addresses)
  const char* kbase[4];
  const char* vbase[4];
  for (int j = 0; j < 4; ++j) {
    int idx = w * 4 + j;
    {
      int row = idx * 4 + lg;                  // kv row in tile
      int swz = (lr * 16) ^ ((row & 7) << 4);  // byte offset in 256B row
      kbase[j] = (const char*)qk +
                 ((size_t)(b * NT + row) * QK_LD + 2048 + h * HD) * 2 + swz;
    }
    {
      int d = idx * 8 + (lane >> 3);
      int cj = (lane & 7) ^ (d & 7);           // 16B source chunk in 128B row
      vbase[j] = (const char*)vT + ((size_t)(bh * HD + d) * NT + cj * 8) * 2;
    }
  }

  // prologue: stage tile 0 -> buf 0 (gated by body 0's vmcnt)
  for (int j = 0; j < 4; ++j) {
    int idx = w * 4 + j;
    gload16(kbase[j], (void*)((char*)Ks[0] + idx * 1024));
    gload16(vbase[j], (void*)((char*)Vs[0] + idx * 1024));
  }

  int cur = 0;
  for (int kt = 0; kt < 32; ++kt) {
    // issue next tile's staging into the other buffer (stays in flight past gate)
    if (kt + 1 < 32) {
      for (int j = 0; j < 4; ++j) {
        int idx = w * 4 + j;
        gload16(kbase[j] + (size_t)(kt + 1) * (64 * QK_LD * 2),
                (void*)((char*)Ks[cur ^ 1] + idx * 1024));
        gload16(vbase[j] + (size_t)(kt + 1) * 128,
                (void*)((char*)Vs[cur ^ 1] + idx * 1024));
      }
    }
    if (kt < 31) asm volatile("s_waitcnt vmcnt(8)" ::: "memory");
    else         asm volatile("s_waitcnt vmcnt(0)" ::: "memory");
    __builtin_amdgcn_s_barrier();
    asm volatile("" ::: "memory");

    // S = Q K^T : both stripes share each K fragment (Q pre-scaled)
    f32x4 sa[2][4] = {};
    for (int nb = 0; nb < 4; ++nb) {
      int kvr = nb * 16 + lr;
      const char* kr = (const char*)Ks[cur] + kvr * 256;
      int s7 = (kvr & 7) << 4;
      for (int dc = 0; dc < 4; ++dc) {
        half8 kb = *(const half8*)(kr + ((dc * 64 + lg * 16) ^ s7));
        sa[0][nb] = __builtin_amdgcn_mfma_f32_16x16x32_f16(qf[0][dc], kb, sa[0][nb], 0, 0, 0);
        sa[1][nb] = __builtin_amdgcn_mfma_f32_16x16x32_f16(qf[1][dc], kb, sa[1][nb], 0, 0, 0);
      }
    }

    // online softmax per stripe (defer-max: skip reduce+rescale unless needed)
    for (int s = 0; s < 2; ++s) {
      float pml[4] = {-1e30f, -1e30f, -1e30f, -1e30f};
      for (int nb = 0; nb < 4; ++nb)
        for (int r = 0; r < 4; ++r)
          pml[r] = fmaxf(pml[r], sa[s][nb][r]);
      bool ok = true;
      for (int r = 0; r < 4; ++r) ok &= (pml[r] <= mrow[s][r] + 8.0f);
      if (!__all(ok)) {
        for (int r = 0; r < 4; ++r) {
          for (int off = 1; off < 16; off <<= 1)
            pml[r] = fmaxf(pml[r], __shfl_xor(pml[r], off));
          float mn = fmaxf(mrow[s][r], pml[r]);
          float al = __expf(mrow[s][r] - mn);
          mrow[s][r] = mn;
          lacc[s][r] *= al;
          for (int db = 0; db < 8; ++db) accy[s][db][r] *= al;
        }
      }
      for (int nb = 0; nb < 4; ++nb)
        for (int r = 0; r < 4; ++r) {
          float p = __expf(sa[s][nb][r] - mrow[s][r]);
          int prow = lg * 4 + r;
          int chunk = (nb * 2 + (lr >> 3)) ^ (prow & 7);
          Ps[w][s][prow * 64 + chunk * 8 + (lr & 7)] = (f16)p;
        }
    }

    // P fragments for both stripes
    half8 pa[2][2];
    for (int s = 0; s < 2; ++s)
      for (int kc = 0; kc < 2; ++kc) {
        int chunk = (kc * 4 + lg) ^ (lr & 7);
        pa[s][kc] = *(const half8*)(&Ps[w][s][lr * 64 + chunk * 8]);
      }
    // row-sum via MFMA against all-ones B (matrix pipe, overlaps VALU softmax)
    for (int s = 0; s < 2; ++s)
      for (int kc = 0; kc < 2; ++kc)
        lacc[s] = __builtin_amdgcn_mfma_f32_16x16x32_f16(pa[s][kc], onev, lacc[s], 0, 0, 0);

    // PV: both stripes share each V fragment
    for (int db = 0; db < 8; ++db) {
      int d = db * 16 + lr;
      const char* vr = (const char*)Vs[cur] + d * 128;
      int d7 = d & 7;
      for (int kc = 0; kc < 2; ++kc) {
        half8 vb = *(const half8*)(vr + (((kc * 4 + lg) ^ d7) * 16));
        accy[0][db] = __builtin_amdgcn_mfma_f32_16x16x32_f16(pa[0][kc], vb, accy[0][db], 0, 0, 0);
        accy[1][db] = __builtin_amdgcn_mfma_f32_16x16x32_f16(pa[1][kc], vb, accy[1][db], 0, 0, 0);
      }
    }

    asm volatile("" ::: "memory");
    __builtin_amdgcn_s_barrier();   // all reads of buf cur done; buf free for kt+2
    cur ^= 1;
  }

  for (int s = 0; s < 2; ++s) {
    f32x4 inv;
    for (int r = 0; r < 4; ++r) inv[r] = 1.0f / lacc[s][r];
    f16* yp = y + (size_t)(b * NT + qt * 128 + w * 32 + s * 16 + lg * 4) * NC +
              h * HD + lr;
    for (int db = 0; db < 8; ++db)
      for (int r = 0; r < 4; ++r)
        yp[(size_t)r * NC + db * 16] = (f16)(accy[s][db][r] * inv[r]);
  }
}

// ---------------- launcher ----------------
extern "C" void kernel_launch(void* const* d_in, const int* in_sizes, int n_in,
                              void* d_out, int out_size, void* d_ws, size_t ws_size,
                              hipStream_t stream) {
  (void)in_sizes; (void)n_in; (void)out_size; (void)ws_size;
  const float* x      = (const float*)d_in[0];
  const float* w_attn = (const float*)d_in[1];
  const float* b_attn = (const float*)d_in[2];
  const float* w_proj = (const float*)d_in[3];
  const float* b_proj = (const float*)d_in[4];
  float* out = (float*)d_out;

  char* p = (char*)d_ws;
  f16* xh  = (f16*)p; p += (size_t)NM * NC * 2;          // 33.5 MB
  f16* waT = (f16*)p; p += (size_t)N3C * NC * 2;         // 25.2 MB
  f16* wpT = (f16*)p; p += (size_t)NC * NC * 2;          //  8.4 MB
  f16* qkb = (f16*)p; p += (size_t)NM * QK_LD * 2;       // 67.1 MB
  f16* vT  = (f16*)p; p += (size_t)NBAT * NHEAD * HD * NT * 2; // 33.5 MB
  f16* yh  = (f16*)p; p += (size_t)NM * NC * 2;          // 33.5 MB

  cvt_x_f16<<<8192, 256, 0, stream>>>(x, xh);
  cvt_tr_f16<<<dim3(192, 64), 256, 0, stream>>>(w_attn, waT, NC, N3C);
  cvt_tr_f16<<<dim3(64, 64), 256, 0, stream>>>(w_proj, wpT, NC, NC);
  // QKV: M=8192 -> 32 bm, N=6144 -> 24 bn, 768 blocks (div by 8)
  gemm256<1><<<768, 512, 0, stream>>>(xh, waT, b_attn, qkb, vT, nullptr,
                                      N3C, NC, 24);
  attn_fwd<<<1024, 256, 0, stream>>>(qkb, vT, yh);
  // proj: M=8192 -> 32 bm, N=2048 -> 8 bn, 256 blocks (div by 8)
  gemm256<0><<<256, 512, 0, stream>>>(yh, wpT, b_proj, nullptr, nullptr,
                                      out, NC, NC, 8);
}